// Round 9
// baseline (168.804 us; speedup 1.0000x reference)
//
#include <hip/hip_runtime.h>
#include <hip/hip_bf16.h>

#define BB 2
#define SS 2048
#define DD 768
#define HH 12
#define DHH 64
#define WIN 128
#define MM (BB*SS)

typedef __attribute__((ext_vector_type(8))) short bfrag;
typedef __attribute__((ext_vector_type(4))) float f32x4;
typedef __attribute__((ext_vector_type(4))) short s16x4;

#define AS3(p) ((__attribute__((address_space(3))) void*)(p))
#define AS1(p) ((const __attribute__((address_space(1))) void*)(p))

__device__ inline unsigned short f2bf(float f) {
    union { __hip_bfloat16 h; unsigned short u; } cv;
    cv.h = __float2bfloat16(f);
    return cv.u;
}

// Stage a R x 32 bf16 tile (row-major, global stride DD) into LDS via DMA,
// 16B chunks XOR-swizzled: chunk cs at row goes to slot cs ^ ((row>>1)&3).
__device__ inline void stage128(unsigned short* dst, const unsigned short* src,
                                int w4, int l) {
    #pragma unroll
    for (int j = 0; j < 2; j++) {
        int eoff = (w4 * 2 + j) * 512;
        int e = eoff + l * 8;
        int row = e >> 5;
        int k8 = ((e >> 3) & 3) ^ ((row >> 1) & 3);
        __builtin_amdgcn_global_load_lds(AS1(src + (size_t)row * DD + k8 * 8),
                                         AS3(dst + eoff), 16, 0, 0);
    }
}
__device__ inline void stage64(unsigned short* dst, const unsigned short* src,
                               int w4, int l) {
    int eoff = w4 * 512;
    int e = eoff + l * 8;
    int row = e >> 5;
    int k8 = ((e >> 3) & 3) ^ ((row >> 1) & 3);
    __builtin_amdgcn_global_load_lds(AS1(src + (size_t)row * DD + k8 * 8),
                                     AS3(dst + eoff), 16, 0, 0);
}

// ---------------- Kernel 0: pack (round-3 verified) ----------------
// [0,432): W_{Q,K,V} -> Wt ; [432,576): W_O -> Wot ; [576,832): rope ;
// [832,3136): X fp32 -> bf16
__global__ __launch_bounds__(256) void pack_kernel(
    const float* __restrict__ Xq, const float* __restrict__ Xk, const float* __restrict__ Xv,
    const float* __restrict__ Wq, const float* __restrict__ Wk, const float* __restrict__ Wv,
    const float* __restrict__ Wo,
    unsigned short* __restrict__ Wt, unsigned short* __restrict__ Wot,
    float2* __restrict__ rope, unsigned short* __restrict__ Xbf)
{
    __shared__ float T[64][65];
    const int bid = blockIdx.x, t = threadIdx.x;
    if (bid < 432) {
        int proj = bid / 144, rem = bid % 144;
        int h = rem / 12, d0 = (rem % 12) * 64;
        const float* src = (proj == 0 ? Wq : (proj == 1 ? Wk : Wv)) + (size_t)h * DD * DHH;
        int row = t >> 2, c0 = (t & 3) * 16;
        const float4* p4 = reinterpret_cast<const float4*>(src + (size_t)(d0 + row) * DHH + c0);
        float4 x0 = p4[0], x1 = p4[1], x2 = p4[2], x3 = p4[3];
        float* tr = &T[row][c0];
        tr[0]=x0.x; tr[1]=x0.y; tr[2]=x0.z; tr[3]=x0.w;
        tr[4]=x1.x; tr[5]=x1.y; tr[6]=x1.z; tr[7]=x1.w;
        tr[8]=x2.x; tr[9]=x2.y; tr[10]=x2.z; tr[11]=x2.w;
        tr[12]=x3.x; tr[13]=x3.y; tr[14]=x3.z; tr[15]=x3.w;
        __syncthreads();
        int dh = t >> 2;
        unsigned short tmp[16];
        #pragma unroll
        for (int j = 0; j < 16; j++) tmp[j] = f2bf(T[c0 + j][dh]);
        unsigned short* dst = Wt + (size_t)proj * DD * DD + (size_t)(h * 64 + dh) * DD + d0 + c0;
        *reinterpret_cast<bfrag*>(dst)     = *reinterpret_cast<bfrag*>(tmp);
        *reinterpret_cast<bfrag*>(dst + 8) = *reinterpret_cast<bfrag*>(tmp + 8);
    } else if (bid < 576) {
        int id2 = bid - 432;
        int k0 = (id2 / 12) * 64, n0 = (id2 % 12) * 64;
        int row = t >> 2, c0 = (t & 3) * 16;
        const float4* p4 = reinterpret_cast<const float4*>(Wo + (size_t)(k0 + row) * DD + n0 + c0);
        float4 x0 = p4[0], x1 = p4[1], x2 = p4[2], x3 = p4[3];
        float* tr = &T[row][c0];
        tr[0]=x0.x; tr[1]=x0.y; tr[2]=x0.z; tr[3]=x0.w;
        tr[4]=x1.x; tr[5]=x1.y; tr[6]=x1.z; tr[7]=x1.w;
        tr[8]=x2.x; tr[9]=x2.y; tr[10]=x2.z; tr[11]=x2.w;
        tr[12]=x3.x; tr[13]=x3.y; tr[14]=x3.z; tr[15]=x3.w;
        __syncthreads();
        int nr = t >> 2;
        unsigned short tmp[16];
        #pragma unroll
        for (int j = 0; j < 16; j++) tmp[j] = f2bf(T[c0 + j][nr]);
        unsigned short* dst = Wot + (size_t)(n0 + nr) * DD + k0 + c0;
        *reinterpret_cast<bfrag*>(dst)     = *reinterpret_cast<bfrag*>(tmp);
        *reinterpret_cast<bfrag*>(dst + 8) = *reinterpret_cast<bfrag*>(tmp + 8);
    } else if (bid < 832) {
        int idx = (bid - 576) * 256 + t;   // p in [0,2048), i2 in [0,32)
        int p = idx >> 5, i2 = idx & 31;
        float inv_freq = exp2f(-(float)i2 * (13.287712379549449f / 32.0f));
        float s, c;
        sincosf((float)p * inv_freq, &s, &c);
        rope[idx] = make_float2(s, c);
    } else {
        int i = bid - 832;                  // 2304 blocks x 4096 elems
        int proj = i / 768;
        size_t off = (size_t)(i % 768) * 4096 + t * 16;
        const float* src = (proj == 0 ? Xq : (proj == 1 ? Xk : Xv)) + off;
        const float4* p4 = reinterpret_cast<const float4*>(src);
        float4 a0 = p4[0], a1 = p4[1], a2 = p4[2], a3 = p4[3];
        unsigned short u[16];
        u[0]=f2bf(a0.x); u[1]=f2bf(a0.y); u[2]=f2bf(a0.z); u[3]=f2bf(a0.w);
        u[4]=f2bf(a1.x); u[5]=f2bf(a1.y); u[6]=f2bf(a1.z); u[7]=f2bf(a1.w);
        u[8]=f2bf(a2.x); u[9]=f2bf(a2.y); u[10]=f2bf(a2.z); u[11]=f2bf(a2.w);
        u[12]=f2bf(a3.x); u[13]=f2bf(a3.y); u[14]=f2bf(a3.z); u[15]=f2bf(a3.w);
        unsigned short* dst = Xbf + (size_t)proj * MM * DD + off;
        *reinterpret_cast<bfrag*>(dst)     = *reinterpret_cast<bfrag*>(u);
        *reinterpret_cast<bfrag*>(dst + 8) = *reinterpret_cast<bfrag*>(u + 8);
    }
}

// ---------------- Kernel 1: QKV GEMM, 128x64 tile + XCD-chunked swizzle --------
// NEW (this round): grid flattened to 1D 1152 with bijective XCD-chunk swizzle
// (T1; 1152 % 8 == 0). Natural order is preserved within each 144-block chunk,
// so the 32 consecutive blocks sharing one W-panel land on the SAME XCD's L2:
// staging DMAs hit L2 (~200cy) instead of HBM (~900cy) -> smaller exposed
// wait per iter in this latency-bound kernel. FETCH_SIZE should drop 38->~30MB.
// Rest identical to round-7 (pure-DMA 3-ring, counted vmcnt(3)).
__global__ __launch_bounds__(256) void qkv_gemm_kernel(
    const unsigned short* __restrict__ Xbf,
    const unsigned short* __restrict__ Wt,
    const float* __restrict__ bq, const float* __restrict__ bk, const float* __restrict__ bv,
    const float2* __restrict__ rope,
    unsigned short* __restrict__ qo, unsigned short* __restrict__ ko, unsigned short* __restrict__ vo)
{
    // bijective XCD swizzle: xcd g gets natural-order chunk [g*144, (g+1)*144)
    const int bl = blockIdx.x;                 // 0..1151
    const int swz_bid = (bl & 7) * 144 + (bl >> 3);
    const int mtile = swz_bid & 31;
    const int rest  = swz_bid >> 5;            // 0..35
    const int proj  = rest / 12;
    const int mt0   = mtile * 128;
    const int n0    = (rest % 12) * 64;

    const unsigned short* X = Xbf + (size_t)proj * MM * DD + (size_t)mt0 * DD;
    const unsigned short* W = Wt + (size_t)proj * DD * DD + (size_t)n0 * DD;
    const float* bias = proj == 0 ? bq : (proj == 1 ? bk : bv);

    // slot: A[0,4096) B[4096,6144) shorts; ring of 3 = 36864B
    __shared__ unsigned short smem[3 * 6144];

    const int t = threadIdx.x;
    const int l = t & 63, w4 = t >> 6;
    const int l16 = l & 15, quad = l >> 4;
    const int swz = (l16 >> 1) & 3;

    f32x4 acc[8] = {};

    // prologue: tiles 0,1 in flight (6 DMA/wave)
    stage128(smem,               X,      w4, l);
    stage64 (smem + 4096,        W,      w4, l);
    stage128(smem + 6144,        X + 32, w4, l);
    stage64 (smem + 6144 + 4096, W + 32, w4, l);

    for (int it = 0; it < 24; ++it) {
        unsigned short* Ac = smem + (it % 3) * 6144;
        unsigned short* Bc = Ac + 4096;
        if (it < 23) asm volatile("s_waitcnt vmcnt(3)" ::: "memory");
        else         asm volatile("s_waitcnt vmcnt(0)" ::: "memory");
        __builtin_amdgcn_s_barrier();
        if (it < 22) {
            unsigned short* An = smem + ((it + 2) % 3) * 6144;
            stage128(An,        X + (it + 2) * 32, w4, l);
            stage64 (An + 4096, W + (it + 2) * 32, w4, l);
        }
        bfrag af[2], bg[4];
        #pragma unroll
        for (int mi = 0; mi < 2; mi++)
            af[mi] = *reinterpret_cast<const bfrag*>(&Ac[(w4 * 32 + mi * 16 + l16) * 32 + ((quad ^ swz) * 8)]);
        #pragma unroll
        for (int ni = 0; ni < 4; ni++)
            bg[ni] = *reinterpret_cast<const bfrag*>(&Bc[(ni * 16 + l16) * 32 + ((quad ^ swz) * 8)]);
        #pragma unroll
        for (int mi = 0; mi < 2; mi++)
            #pragma unroll
            for (int ni = 0; ni < 4; ni++)
                acc[mi * 4 + ni] = __builtin_amdgcn_mfma_f32_16x16x32_bf16(af[mi], bg[ni], acc[mi * 4 + ni], 0, 0, 0);
    }
    __syncthreads();

    unsigned short* Ct = smem;
    const int b = mt0 >> 11;
    if (proj < 2) {
        // Ct stride 72: [128 p][64 n]
        #pragma unroll
        for (int ni = 0; ni < 4; ni++) {
            int nloc = ni * 16 + l16;          // 0..63
            int n = n0 + nloc;
            int dh = n & 63;                   // == nloc
            float bv0 = bias[n];
            float bv1 = bias[n ^ 32];
            float sgn = (dh & 32) ? 1.0f : -1.0f;
            const float2* rp = rope + (dh & 31);
            #pragma unroll
            for (int mi = 0; mi < 2; mi++)
                #pragma unroll
                for (int r = 0; r < 4; r++) {
                    int ploc = w4 * 32 + mi * 16 + quad * 4 + r;
                    int p = (mt0 + ploc) & (SS - 1);
                    float2 sc = rp[p << 5];
                    float val = acc[mi * 4 + ni][r] + bv0;
                    float pr  = acc[mi * 4 + (ni ^ 2)][r] + bv1;
                    Ct[ploc * 72 + nloc] = f2bf(val * sc.y + sgn * pr * sc.x);
                }
        }
        __syncthreads();
        unsigned short* dst = (proj == 0) ? qo : ko;
        const int h = n0 >> 6;
        #pragma unroll
        for (int jj = 0; jj < 4; jj++) {
            int id = jj * 256 + t;             // 0..1023
            int row = id >> 3, c = (id & 7) * 8;
            int p = (mt0 + row) & (SS - 1);
            bfrag vv = *reinterpret_cast<const bfrag*>(&Ct[row * 72 + c]);
            *reinterpret_cast<bfrag*>(dst + (((size_t)(b * HH + h) * SS + p) << 6) + (n0 & 63) + c) = vv;
        }
    } else {
        // Ct stride 136: [64 n][128 p] (transposed for V layout)
        #pragma unroll
        for (int ni = 0; ni < 4; ni++) {
            int nloc = ni * 16 + l16;
            float bv0 = bias[n0 + nloc];
            #pragma unroll
            for (int mi = 0; mi < 2; mi++)
                #pragma unroll
                for (int r = 0; r < 4; r++) {
                    int ploc = w4 * 32 + mi * 16 + quad * 4 + r;
                    Ct[nloc * 136 + ploc] = f2bf(acc[mi * 4 + ni][r] + bv0);
                }
        }
        __syncthreads();
        int p0 = mt0 & (SS - 1);
        const int h = n0 >> 6;
        #pragma unroll
        for (int jj = 0; jj < 4; jj++) {
            int id = jj * 256 + t;             // 0..1023
            int row = id >> 4, c = (id & 15) * 8;
            int dh = (n0 & 63) + row;          // n0 64-aligned => dh = row
            bfrag vv = *reinterpret_cast<const bfrag*>(&Ct[row * 136 + c]);
            *reinterpret_cast<bfrag*>(vo + (((size_t)(b * HH + h) * DHH + dh) << 11) + p0 + c) = vv;
        }
    }
}

// ---------------- Kernel 2: sliding-window attention, band-skip (round-7) ------
// REVERTED (this round): V-staging restored. Round-8's V-direct put ~200cy L2
// latency on the PV MFMA operand chain with no prefetch distance -> slight
// regression despite 5 blocks/CU. Staged V insulates the MFMA chain.
__global__ __launch_bounds__(256) void attn_kernel(
    const unsigned short* __restrict__ q,
    const unsigned short* __restrict__ k,
    const unsigned short* __restrict__ v,
    unsigned short* __restrict__ z)
{
    const int qb = blockIdx.x * 64;
    const int h  = blockIdx.y;
    const int b  = blockIdx.z;
    const int kb = qb - WIN;   // may be negative: reads land in prior ws slab (masked)

    // K panels [0,12288); P aliases [0,12800); Vt [12800,25088)
    __shared__ unsigned short sA[25088];

    const int t = threadIdx.x;
    const int w4 = t >> 6, l = t & 63;
    const int l16 = l & 15, quad = l >> 4;
    const int swz = (l16 >> 1) & 3;

    const size_t qkbase = (size_t)(b * HH + h) * SS * DHH;
    const unsigned short* kp = (k + qkbase) + (ptrdiff_t)kb * DHH;
    const unsigned short* vp = (v + (size_t)(b * HH + h) * DHH * SS) + (ptrdiff_t)kb;

    #pragma unroll
    for (int j = 0; j < 6; j++) {
        int g = w4 * 6 + j;
        int panel = g >> 2, sub = g & 3;
        int rg = panel >> 1, kpart = panel & 1;
        int e = sub * 512 + l * 8;
        int row = e >> 5;
        int k8 = ((e >> 3) & 3) ^ ((row >> 1) & 3);
        __builtin_amdgcn_global_load_lds(
            AS1(kp + (size_t)(rg * 64 + row) * DHH + kpart * 32 + k8 * 8),
            AS3(sA + panel * 2048 + sub * 512), 16, 0, 0);
    }
    #pragma unroll
    for (int j = 0; j < 6; j++) {
        int g = w4 * 6 + j;
        int F = g * 64 + l;               // flat 16B-chunk id, 0..1535
        int d = F / 24, s = F % 24;
        int cs = s ^ (d & 7);
        __builtin_amdgcn_global_load_lds(
            AS1(vp + (size_t)d * SS + cs * 8),
            AS3(sA + 12800 + g * 512), 16, 0, 0);
    }
    bfrag qf[2];
    #pragma unroll
    for (int kk = 0; kk < 2; kk++)
        qf[kk] = *reinterpret_cast<const bfrag*>(
            q + qkbase + (size_t)(qb + 16 * w4 + l16) * DHH + kk * 32 + quad * 8);

    __syncthreads();   // K + V resident

    f32x4 sacc[9] = {};
    __builtin_amdgcn_s_setprio(1);
    #pragma unroll
    for (int kk = 0; kk < 2; kk++)
        #pragma unroll
        for (int j = 0; j < 9; j++) {
            int kr = 16 * (w4 + j) + l16;
            bfrag bf = *reinterpret_cast<const bfrag*>(
                &sA[(((kr >> 6) * 2 + kk) * 2048) + (kr & 63) * 32 + ((quad ^ swz) * 8)]);
            sacc[j] = __builtin_amdgcn_mfma_f32_16x16x32_bf16(qf[kk], bf, sacc[j], 0, 0, 0);
        }
    __builtin_amdgcn_s_setprio(0);

    float mx[4] = {-3e38f, -3e38f, -3e38f, -3e38f};
    #pragma unroll
    for (int j = 0; j < 9; j++)
        #pragma unroll
        for (int r = 0; r < 4; r++) {
            int row = 16 * w4 + quad * 4 + r;
            int c = 16 * (w4 + j) + l16;
            bool valid = (c > row) && (c <= row + WIN) && (kb + c >= 0);
            float s = valid ? sacc[j][r] * 0.125f : -3e38f;
            sacc[j][r] = s;
            mx[r] = fmaxf(mx[r], s);
        }
    #pragma unroll
    for (int off = 1; off < 16; off <<= 1)
        #pragma unroll
        for (int r = 0; r < 4; r++) mx[r] = fmaxf(mx[r], __shfl_xor(mx[r], off, 64));
    float sum[4] = {0.f, 0.f, 0.f, 0.f};
    #pragma unroll
    for (int j = 0; j < 9; j++)
        #pragma unroll
        for (int r = 0; r < 4; r++) {
            float p = __expf(sacc[j][r] - mx[r]);
            sacc[j][r] = p;
            sum[r] += p;
        }
    #pragma unroll
    for (int off = 1; off < 16; off <<= 1)
        #pragma unroll
        for (int r = 0; r < 4; r++) sum[r] += __shfl_xor(sum[r], off, 64);
    float inv[4];
    #pragma unroll
    for (int r = 0; r < 4; r++) inv[r] = 1.0f / sum[r];

    __syncthreads();   // all K reads done before P overwrites that region

    unsigned short* Ps = sA;
    #pragma unroll
    for (int j = 0; j < 9; j++)
        #pragma unroll
        for (int r = 0; r < 4; r++)
            Ps[(16 * w4 + quad * 4 + r) * 200 + 16 * (w4 + j) + l16] = f2bf(sacc[j][r] * inv[r]);
    // zero the single tile inside the PV read-window that QK^T skipped
    {
        int mtz = (w4 & 1) ? (w4 - 1) : (w4 + 9);
        #pragma unroll
        for (int r = 0; r < 4; r++)
            Ps[(16 * w4 + quad * 4 + r) * 200 + 16 * mtz + l16] = 0;
    }

    unsigned short* Vt = sA + 12800;
    f32x4 zacc[4] = {};
    __builtin_amdgcn_s_setprio(1);
    #pragma unroll
    for (int ji = 0; ji < 5; ji++) {
        int ci = (w4 >> 1) + ji;
        bfrag pb = *reinterpret_cast<const bfrag*>(
            &Ps[(16 * w4 + l16) * 200 + ci * 32 + quad * 8]);
        #pragma unroll
        for (int mt = 0; mt < 4; mt++) {
            int d = 16 * mt + l16;
            bfrag va = *reinterpret_cast<const bfrag*>(
                &Vt[d * 192 + (((ci * 4 + quad) ^ (l16 & 7)) * 8)]);
            zacc[mt] = __builtin_amdgcn_mfma_f32_16x16x32_bf16(va, pb, zacc[mt], 0, 0, 0);
        }
    }
    __builtin_amdgcn_s_setprio(0);
    size_t zrow = ((size_t)(b * SS + qb + 16 * w4 + l16)) * (HH * DHH) + h * DHH;
    #pragma unroll
    for (int mt = 0; mt < 4; mt++) {
        s16x4 pk;
        pk[0] = (short)f2bf(zacc[mt][0]);
        pk[1] = (short)f2bf(zacc[mt][1]);
        pk[2] = (short)f2bf(zacc[mt][2]);
        pk[3] = (short)f2bf(zacc[mt][3]);
        *reinterpret_cast<s16x4*>(z + zrow + 16 * mt + quad * 4) = pk;
    }
}

// ---------------- Kernel 3: output projection, 64x64 tile, BK=64 (round-3) ----
__global__ __launch_bounds__(256) void out_gemm_kernel(
    const unsigned short* __restrict__ Z,
    const unsigned short* __restrict__ Wot,
    const float* __restrict__ bo,
    float* __restrict__ out)
{
    const int mt0 = blockIdx.x * 64;
    const int n0  = blockIdx.y * 64;
    const unsigned short* A = Z + (size_t)mt0 * DD;
    const unsigned short* Bw = Wot + (size_t)n0 * DD;

    // slot: [A0 2048][A1 2048][B0 2048][B1 2048] shorts = 16KB; ring of 3
    __shared__ unsigned short smem[3 * 8192];

    const int t = threadIdx.x;
    const int l = t & 63, w4 = t >> 6;
    const int l16 = l & 15, quad = l >> 4;
    const int swz = (l16 >> 1) & 3;

    f32x4 acc[4] = {};

    // prologue: slots 0 (k=0..63) and 1 (k=64..127) in flight: 8 DMA/wave
    #pragma unroll
    for (int s = 0; s < 2; s++) {
        unsigned short* sl = smem + s * 8192;
        stage64(sl,        A  + s * 64,      w4, l);
        stage64(sl + 2048, A  + s * 64 + 32, w4, l);
        stage64(sl + 4096, Bw + s * 64,      w4, l);
        stage64(sl + 6144, Bw + s * 64 + 32, w4, l);
    }

    for (int it = 0; it < 12; ++it) {
        unsigned short* Ac = smem + (it % 3) * 8192;
        unsigned short* Bc = Ac + 4096;
        if (it < 11) asm volatile("s_waitcnt vmcnt(4)" ::: "memory");
        else         asm volatile("s_waitcnt vmcnt(0)" ::: "memory");
        __builtin_amdgcn_s_barrier();
        if (it < 10) {
            unsigned short* An = smem + ((it + 2) % 3) * 8192;
            stage64(An,        A  + (it + 2) * 64,      w4, l);
            stage64(An + 2048, A  + (it + 2) * 64 + 32, w4, l);
            stage64(An + 4096, Bw + (it + 2) * 64,      w4, l);
            stage64(An + 6144, Bw + (it + 2) * 64 + 32, w4, l);
        }
        #pragma unroll
        for (int kk = 0; kk < 2; kk++) {
            bfrag af = *reinterpret_cast<const bfrag*>(
                &Ac[kk * 2048 + (w4 * 16 + l16) * 32 + ((quad ^ swz) * 8)]);
            #pragma unroll
            for (int ni = 0; ni < 4; ni++) {
                bfrag bg = *reinterpret_cast<const bfrag*>(
                    &Bc[kk * 2048 + (ni * 16 + l16) * 32 + ((quad ^ swz) * 8)]);
                acc[ni] = __builtin_amdgcn_mfma_f32_16x16x32_bf16(af, bg, acc[ni], 0, 0, 0);
            }
        }
    }

    #pragma unroll
    for (int ni = 0; ni < 4; ni++) {
        int n = n0 + ni * 16 + l16;
        float bv0 = bo[n];
        #pragma unroll
        for (int r = 0; r < 4; r++) {
            int m = mt0 + w4 * 16 + quad * 4 + r;
            out[(size_t)m * DD + n] = acc[ni][r] + bv0;
        }
    }
}

extern "C" void kernel_launch(void* const* d_in, const int* in_sizes, int n_in,
                              void* d_out, int out_size, void* d_ws, size_t ws_size,
                              hipStream_t stream) {
    const float* Xq = (const float*)d_in[0];
    const float* Xk = (const float*)d_in[1];
    const float* Xv = (const float*)d_in[2];
    const float* Wq = (const float*)d_in[3];
    const float* Wk = (const float*)d_in[4];
    const float* Wv = (const float*)d_in[5];
    const float* Wo = (const float*)d_in[6];
    const float* bq = (const float*)d_in[7];
    const float* bk = (const float*)d_in[8];
    const float* bv = (const float*)d_in[9];
    const float* bo = (const float*)d_in[10];
    float* out = (float*)d_out;

    const size_t seg = (size_t)BB * HH * SS * DHH;   // 3,145,728 bf16 elems
    unsigned short* q   = (unsigned short*)d_ws;
    unsigned short* k   = q + seg;
    unsigned short* v   = k + seg;
    unsigned short* z   = v + seg;
    unsigned short* Wt  = z + seg;                    // 3*768*768
    unsigned short* Wot = Wt + (size_t)3 * DD * DD;   // 768*768
    float2* rope = (float2*)(Wot + (size_t)DD * DD);  // 2048*32 float2
    unsigned short* Xbf = (unsigned short*)(rope + 2048 * 32); // 3*4096*768

    pack_kernel<<<dim3(3136), 256, 0, stream>>>(Xq, Xk, Xv, Wq, Wk, Wv, Wo, Wt, Wot, rope, Xbf);
    qkv_gemm_kernel<<<dim3(1152), 256, 0, stream>>>(
        Xbf, Wt, bq, bk, bv, rope, q, k, v);
    attn_kernel<<<dim3(SS / 64, HH, BB), 256, 0, stream>>>(q, k, v, z);
    out_gemm_kernel<<<dim3(MM / 64, DD / 64), 256, 0, stream>>>(z, Wot, bo, out);
}

// Round 12
// 160.551 us; speedup vs baseline: 1.0514x; 1.0514x over previous
//
#include <hip/hip_runtime.h>
#include <hip/hip_bf16.h>

#define BB 2
#define SS 2048
#define DD 768
#define HH 12
#define DHH 64
#define WIN 128
#define MM (BB*SS)

typedef __attribute__((ext_vector_type(8))) short bfrag;
typedef __attribute__((ext_vector_type(4))) float f32x4;
typedef __attribute__((ext_vector_type(4))) short s16x4;

#define AS3(p) ((__attribute__((address_space(3))) void*)(p))
#define AS1(p) ((const __attribute__((address_space(1))) void*)(p))

__device__ inline unsigned short f2bf(float f) {
    union { __hip_bfloat16 h; unsigned short u; } cv;
    cv.h = __float2bfloat16(f);
    return cv.u;
}

// Stage a R x 32 bf16 tile (row-major, global stride DD) into LDS via DMA,
// 16B chunks XOR-swizzled: chunk cs at row goes to slot cs ^ ((row>>1)&3).
__device__ inline void stage128(unsigned short* dst, const unsigned short* src,
                                int w4, int l) {
    #pragma unroll
    for (int j = 0; j < 2; j++) {
        int eoff = (w4 * 2 + j) * 512;
        int e = eoff + l * 8;
        int row = e >> 5;
        int k8 = ((e >> 3) & 3) ^ ((row >> 1) & 3);
        __builtin_amdgcn_global_load_lds(AS1(src + (size_t)row * DD + k8 * 8),
                                         AS3(dst + eoff), 16, 0, 0);
    }
}
__device__ inline void stage64(unsigned short* dst, const unsigned short* src,
                               int w4, int l) {
    int eoff = w4 * 512;
    int e = eoff + l * 8;
    int row = e >> 5;
    int k8 = ((e >> 3) & 3) ^ ((row >> 1) & 3);
    __builtin_amdgcn_global_load_lds(AS1(src + (size_t)row * DD + k8 * 8),
                                     AS3(dst + eoff), 16, 0, 0);
}

// ---------------- Kernel 0: pack (round-3 verified) ----------------
// [0,432): W_{Q,K,V} -> Wt ; [432,576): W_O -> Wot ; [576,832): rope ;
// [832,3136): X fp32 -> bf16
__global__ __launch_bounds__(256) void pack_kernel(
    const float* __restrict__ Xq, const float* __restrict__ Xk, const float* __restrict__ Xv,
    const float* __restrict__ Wq, const float* __restrict__ Wk, const float* __restrict__ Wv,
    const float* __restrict__ Wo,
    unsigned short* __restrict__ Wt, unsigned short* __restrict__ Wot,
    float2* __restrict__ rope, unsigned short* __restrict__ Xbf)
{
    __shared__ float T[64][65];
    const int bid = blockIdx.x, t = threadIdx.x;
    if (bid < 432) {
        int proj = bid / 144, rem = bid % 144;
        int h = rem / 12, d0 = (rem % 12) * 64;
        const float* src = (proj == 0 ? Wq : (proj == 1 ? Wk : Wv)) + (size_t)h * DD * DHH;
        int row = t >> 2, c0 = (t & 3) * 16;
        const float4* p4 = reinterpret_cast<const float4*>(src + (size_t)(d0 + row) * DHH + c0);
        float4 x0 = p4[0], x1 = p4[1], x2 = p4[2], x3 = p4[3];
        float* tr = &T[row][c0];
        tr[0]=x0.x; tr[1]=x0.y; tr[2]=x0.z; tr[3]=x0.w;
        tr[4]=x1.x; tr[5]=x1.y; tr[6]=x1.z; tr[7]=x1.w;
        tr[8]=x2.x; tr[9]=x2.y; tr[10]=x2.z; tr[11]=x2.w;
        tr[12]=x3.x; tr[13]=x3.y; tr[14]=x3.z; tr[15]=x3.w;
        __syncthreads();
        int dh = t >> 2;
        unsigned short tmp[16];
        #pragma unroll
        for (int j = 0; j < 16; j++) tmp[j] = f2bf(T[c0 + j][dh]);
        unsigned short* dst = Wt + (size_t)proj * DD * DD + (size_t)(h * 64 + dh) * DD + d0 + c0;
        *reinterpret_cast<bfrag*>(dst)     = *reinterpret_cast<bfrag*>(tmp);
        *reinterpret_cast<bfrag*>(dst + 8) = *reinterpret_cast<bfrag*>(tmp + 8);
    } else if (bid < 576) {
        int id2 = bid - 432;
        int k0 = (id2 / 12) * 64, n0 = (id2 % 12) * 64;
        int row = t >> 2, c0 = (t & 3) * 16;
        const float4* p4 = reinterpret_cast<const float4*>(Wo + (size_t)(k0 + row) * DD + n0 + c0);
        float4 x0 = p4[0], x1 = p4[1], x2 = p4[2], x3 = p4[3];
        float* tr = &T[row][c0];
        tr[0]=x0.x; tr[1]=x0.y; tr[2]=x0.z; tr[3]=x0.w;
        tr[4]=x1.x; tr[5]=x1.y; tr[6]=x1.z; tr[7]=x1.w;
        tr[8]=x2.x; tr[9]=x2.y; tr[10]=x2.z; tr[11]=x2.w;
        tr[12]=x3.x; tr[13]=x3.y; tr[14]=x3.z; tr[15]=x3.w;
        __syncthreads();
        int nr = t >> 2;
        unsigned short tmp[16];
        #pragma unroll
        for (int j = 0; j < 16; j++) tmp[j] = f2bf(T[c0 + j][nr]);
        unsigned short* dst = Wot + (size_t)(n0 + nr) * DD + k0 + c0;
        *reinterpret_cast<bfrag*>(dst)     = *reinterpret_cast<bfrag*>(tmp);
        *reinterpret_cast<bfrag*>(dst + 8) = *reinterpret_cast<bfrag*>(tmp + 8);
    } else if (bid < 832) {
        int idx = (bid - 576) * 256 + t;   // p in [0,2048), i2 in [0,32)
        int p = idx >> 5, i2 = idx & 31;
        float inv_freq = exp2f(-(float)i2 * (13.287712379549449f / 32.0f));
        float s, c;
        sincosf((float)p * inv_freq, &s, &c);
        rope[idx] = make_float2(s, c);
    } else {
        int i = bid - 832;                  // 2304 blocks x 4096 elems
        int proj = i / 768;
        size_t off = (size_t)(i % 768) * 4096 + t * 16;
        const float* src = (proj == 0 ? Xq : (proj == 1 ? Xk : Xv)) + off;
        const float4* p4 = reinterpret_cast<const float4*>(src);
        float4 a0 = p4[0], a1 = p4[1], a2 = p4[2], a3 = p4[3];
        unsigned short u[16];
        u[0]=f2bf(a0.x); u[1]=f2bf(a0.y); u[2]=f2bf(a0.z); u[3]=f2bf(a0.w);
        u[4]=f2bf(a1.x); u[5]=f2bf(a1.y); u[6]=f2bf(a1.z); u[7]=f2bf(a1.w);
        u[8]=f2bf(a2.x); u[9]=f2bf(a2.y); u[10]=f2bf(a2.z); u[11]=f2bf(a2.w);
        u[12]=f2bf(a3.x); u[13]=f2bf(a3.y); u[14]=f2bf(a3.z); u[15]=f2bf(a3.w);
        unsigned short* dst = Xbf + (size_t)proj * MM * DD + off;
        *reinterpret_cast<bfrag*>(dst)     = *reinterpret_cast<bfrag*>(u);
        *reinterpret_cast<bfrag*>(dst + 8) = *reinterpret_cast<bfrag*>(u + 8);
    }
}

// ---------------- Kernel 1: QKV GEMM, 128x64 tile, pure-DMA (round-7 verified) -
// 3D grid (32,12,3): natural order already gives W-panel sharing to consecutive
// blocks (x fastest). 1152 blocks, 36KB LDS -> 4 blocks/CU. Counted vmcnt(3).
__global__ __launch_bounds__(256) void qkv_gemm_kernel(
    const unsigned short* __restrict__ Xbf,
    const unsigned short* __restrict__ Wt,
    const float* __restrict__ bq, const float* __restrict__ bk, const float* __restrict__ bv,
    const float2* __restrict__ rope,
    unsigned short* __restrict__ qo, unsigned short* __restrict__ ko, unsigned short* __restrict__ vo)
{
    const int mt0  = blockIdx.x * 128;
    const int n0   = blockIdx.y * 64;
    const int proj = blockIdx.z;
    const unsigned short* X = Xbf + (size_t)proj * MM * DD + (size_t)mt0 * DD;
    const unsigned short* W = Wt + (size_t)proj * DD * DD + (size_t)n0 * DD;
    const float* bias = proj == 0 ? bq : (proj == 1 ? bk : bv);

    // slot: A[0,4096) B[4096,6144) shorts; ring of 3 = 36864B
    __shared__ unsigned short smem[3 * 6144];

    const int t = threadIdx.x;
    const int l = t & 63, w4 = t >> 6;
    const int l16 = l & 15, quad = l >> 4;
    const int swz = (l16 >> 1) & 3;

    f32x4 acc[8] = {};

    // prologue: tiles 0,1 in flight (6 DMA/wave)
    stage128(smem,               X,      w4, l);
    stage64 (smem + 4096,        W,      w4, l);
    stage128(smem + 6144,        X + 32, w4, l);
    stage64 (smem + 6144 + 4096, W + 32, w4, l);

    for (int it = 0; it < 24; ++it) {
        unsigned short* Ac = smem + (it % 3) * 6144;
        unsigned short* Bc = Ac + 4096;
        if (it < 23) asm volatile("s_waitcnt vmcnt(3)" ::: "memory");
        else         asm volatile("s_waitcnt vmcnt(0)" ::: "memory");
        __builtin_amdgcn_s_barrier();
        if (it < 22) {
            unsigned short* An = smem + ((it + 2) % 3) * 6144;
            stage128(An,        X + (it + 2) * 32, w4, l);
            stage64 (An + 4096, W + (it + 2) * 32, w4, l);
        }
        bfrag af[2], bg[4];
        #pragma unroll
        for (int mi = 0; mi < 2; mi++)
            af[mi] = *reinterpret_cast<const bfrag*>(&Ac[(w4 * 32 + mi * 16 + l16) * 32 + ((quad ^ swz) * 8)]);
        #pragma unroll
        for (int ni = 0; ni < 4; ni++)
            bg[ni] = *reinterpret_cast<const bfrag*>(&Bc[(ni * 16 + l16) * 32 + ((quad ^ swz) * 8)]);
        #pragma unroll
        for (int mi = 0; mi < 2; mi++)
            #pragma unroll
            for (int ni = 0; ni < 4; ni++)
                acc[mi * 4 + ni] = __builtin_amdgcn_mfma_f32_16x16x32_bf16(af[mi], bg[ni], acc[mi * 4 + ni], 0, 0, 0);
    }
    __syncthreads();

    unsigned short* Ct = smem;
    const int b = mt0 >> 11;
    if (proj < 2) {
        // Ct stride 72: [128 p][64 n]
        #pragma unroll
        for (int ni = 0; ni < 4; ni++) {
            int nloc = ni * 16 + l16;          // 0..63
            int n = n0 + nloc;
            int dh = n & 63;                   // == nloc
            float bv0 = bias[n];
            float bv1 = bias[n ^ 32];
            float sgn = (dh & 32) ? 1.0f : -1.0f;
            const float2* rp = rope + (dh & 31);
            #pragma unroll
            for (int mi = 0; mi < 2; mi++)
                #pragma unroll
                for (int r = 0; r < 4; r++) {
                    int ploc = w4 * 32 + mi * 16 + quad * 4 + r;
                    int p = (mt0 + ploc) & (SS - 1);
                    float2 sc = rp[p << 5];
                    float val = acc[mi * 4 + ni][r] + bv0;
                    float pr  = acc[mi * 4 + (ni ^ 2)][r] + bv1;
                    Ct[ploc * 72 + nloc] = f2bf(val * sc.y + sgn * pr * sc.x);
                }
        }
        __syncthreads();
        unsigned short* dst = (proj == 0) ? qo : ko;
        const int h = n0 >> 6;
        #pragma unroll
        for (int jj = 0; jj < 4; jj++) {
            int id = jj * 256 + t;             // 0..1023
            int row = id >> 3, c = (id & 7) * 8;
            int p = (mt0 + row) & (SS - 1);
            bfrag vv = *reinterpret_cast<const bfrag*>(&Ct[row * 72 + c]);
            *reinterpret_cast<bfrag*>(dst + (((size_t)(b * HH + h) * SS + p) << 6) + (n0 & 63) + c) = vv;
        }
    } else {
        // Ct stride 136: [64 n][128 p] (transposed for V layout)
        #pragma unroll
        for (int ni = 0; ni < 4; ni++) {
            int nloc = ni * 16 + l16;
            float bv0 = bias[n0 + nloc];
            #pragma unroll
            for (int mi = 0; mi < 2; mi++)
                #pragma unroll
                for (int r = 0; r < 4; r++) {
                    int ploc = w4 * 32 + mi * 16 + quad * 4 + r;
                    Ct[nloc * 136 + ploc] = f2bf(acc[mi * 4 + ni][r] + bv0);
                }
        }
        __syncthreads();
        int p0 = mt0 & (SS - 1);
        const int h = n0 >> 6;
        #pragma unroll
        for (int jj = 0; jj < 4; jj++) {
            int id = jj * 256 + t;             // 0..1023
            int row = id >> 4, c = (id & 15) * 8;
            int dh = (n0 & 63) + row;          // n0 64-aligned => dh = row
            bfrag vv = *reinterpret_cast<const bfrag*>(&Ct[row * 136 + c]);
            *reinterpret_cast<bfrag*>(vo + (((size_t)(b * HH + h) * DHH + dh) << 11) + p0 + c) = vv;
        }
    }
}

// ---------------- Kernel 2: sliding-window attention, band-skip (round-7) ------
// V staged in LDS (insulates the PV MFMA operand chain from global latency;
// V-direct variant measured slightly worse in round 8).
__global__ __launch_bounds__(256) void attn_kernel(
    const unsigned short* __restrict__ q,
    const unsigned short* __restrict__ k,
    const unsigned short* __restrict__ v,
    unsigned short* __restrict__ z)
{
    const int qb = blockIdx.x * 64;
    const int h  = blockIdx.y;
    const int b  = blockIdx.z;
    const int kb = qb - WIN;   // may be negative: reads land in prior ws slab (masked)

    // K panels [0,12288); P aliases [0,12800); Vt [12800,25088)
    __shared__ unsigned short sA[25088];

    const int t = threadIdx.x;
    const int w4 = t >> 6, l = t & 63;
    const int l16 = l & 15, quad = l >> 4;
    const int swz = (l16 >> 1) & 3;

    const size_t qkbase = (size_t)(b * HH + h) * SS * DHH;
    const unsigned short* kp = (k + qkbase) + (ptrdiff_t)kb * DHH;
    const unsigned short* vp = (v + (size_t)(b * HH + h) * DHH * SS) + (ptrdiff_t)kb;

    #pragma unroll
    for (int j = 0; j < 6; j++) {
        int g = w4 * 6 + j;
        int panel = g >> 2, sub = g & 3;
        int rg = panel >> 1, kpart = panel & 1;
        int e = sub * 512 + l * 8;
        int row = e >> 5;
        int k8 = ((e >> 3) & 3) ^ ((row >> 1) & 3);
        __builtin_amdgcn_global_load_lds(
            AS1(kp + (size_t)(rg * 64 + row) * DHH + kpart * 32 + k8 * 8),
            AS3(sA + panel * 2048 + sub * 512), 16, 0, 0);
    }
    #pragma unroll
    for (int j = 0; j < 6; j++) {
        int g = w4 * 6 + j;
        int F = g * 64 + l;               // flat 16B-chunk id, 0..1535
        int d = F / 24, s = F % 24;
        int cs = s ^ (d & 7);
        __builtin_amdgcn_global_load_lds(
            AS1(vp + (size_t)d * SS + cs * 8),
            AS3(sA + 12800 + g * 512), 16, 0, 0);
    }
    bfrag qf[2];
    #pragma unroll
    for (int kk = 0; kk < 2; kk++)
        qf[kk] = *reinterpret_cast<const bfrag*>(
            q + qkbase + (size_t)(qb + 16 * w4 + l16) * DHH + kk * 32 + quad * 8);

    __syncthreads();   // K + V resident

    f32x4 sacc[9] = {};
    __builtin_amdgcn_s_setprio(1);
    #pragma unroll
    for (int kk = 0; kk < 2; kk++)
        #pragma unroll
        for (int j = 0; j < 9; j++) {
            int kr = 16 * (w4 + j) + l16;
            bfrag bf = *reinterpret_cast<const bfrag*>(
                &sA[(((kr >> 6) * 2 + kk) * 2048) + (kr & 63) * 32 + ((quad ^ swz) * 8)]);
            sacc[j] = __builtin_amdgcn_mfma_f32_16x16x32_bf16(qf[kk], bf, sacc[j], 0, 0, 0);
        }
    __builtin_amdgcn_s_setprio(0);

    float mx[4] = {-3e38f, -3e38f, -3e38f, -3e38f};
    #pragma unroll
    for (int j = 0; j < 9; j++)
        #pragma unroll
        for (int r = 0; r < 4; r++) {
            int row = 16 * w4 + quad * 4 + r;
            int c = 16 * (w4 + j) + l16;
            bool valid = (c > row) && (c <= row + WIN) && (kb + c >= 0);
            float s = valid ? sacc[j][r] * 0.125f : -3e38f;
            sacc[j][r] = s;
            mx[r] = fmaxf(mx[r], s);
        }
    #pragma unroll
    for (int off = 1; off < 16; off <<= 1)
        #pragma unroll
        for (int r = 0; r < 4; r++) mx[r] = fmaxf(mx[r], __shfl_xor(mx[r], off, 64));
    float sum[4] = {0.f, 0.f, 0.f, 0.f};
    #pragma unroll
    for (int j = 0; j < 9; j++)
        #pragma unroll
        for (int r = 0; r < 4; r++) {
            float p = __expf(sacc[j][r] - mx[r]);
            sacc[j][r] = p;
            sum[r] += p;
        }
    #pragma unroll
    for (int off = 1; off < 16; off <<= 1)
        #pragma unroll
        for (int r = 0; r < 4; r++) sum[r] += __shfl_xor(sum[r], off, 64);
    float inv[4];
    #pragma unroll
    for (int r = 0; r < 4; r++) inv[r] = 1.0f / sum[r];

    __syncthreads();   // all K reads done before P overwrites that region

    unsigned short* Ps = sA;
    #pragma unroll
    for (int j = 0; j < 9; j++)
        #pragma unroll
        for (int r = 0; r < 4; r++)
            Ps[(16 * w4 + quad * 4 + r) * 200 + 16 * (w4 + j) + l16] = f2bf(sacc[j][r] * inv[r]);
    // zero the single tile inside the PV read-window that QK^T skipped
    {
        int mtz = (w4 & 1) ? (w4 - 1) : (w4 + 9);
        #pragma unroll
        for (int r = 0; r < 4; r++)
            Ps[(16 * w4 + quad * 4 + r) * 200 + 16 * mtz + l16] = 0;
    }

    unsigned short* Vt = sA + 12800;
    f32x4 zacc[4] = {};
    __builtin_amdgcn_s_setprio(1);
    #pragma unroll
    for (int ji = 0; ji < 5; ji++) {
        int ci = (w4 >> 1) + ji;
        bfrag pb = *reinterpret_cast<const bfrag*>(
            &Ps[(16 * w4 + l16) * 200 + ci * 32 + quad * 8]);
        #pragma unroll
        for (int mt = 0; mt < 4; mt++) {
            int d = 16 * mt + l16;
            bfrag va = *reinterpret_cast<const bfrag*>(
                &Vt[d * 192 + (((ci * 4 + quad) ^ (l16 & 7)) * 8)]);
            zacc[mt] = __builtin_amdgcn_mfma_f32_16x16x32_bf16(va, pb, zacc[mt], 0, 0, 0);
        }
    }
    __builtin_amdgcn_s_setprio(0);
    size_t zrow = ((size_t)(b * SS + qb + 16 * w4 + l16)) * (HH * DHH) + h * DHH;
    #pragma unroll
    for (int mt = 0; mt < 4; mt++) {
        s16x4 pk;
        pk[0] = (short)f2bf(zacc[mt][0]);
        pk[1] = (short)f2bf(zacc[mt][1]);
        pk[2] = (short)f2bf(zacc[mt][2]);
        pk[3] = (short)f2bf(zacc[mt][3]);
        *reinterpret_cast<s16x4*>(z + zrow + 16 * mt + quad * 4) = pk;
    }
}

// ---------------- Kernel 3: output projection, 64x64 tile, BK=64 (round-3) ----
__global__ __launch_bounds__(256) void out_gemm_kernel(
    const unsigned short* __restrict__ Z,
    const unsigned short* __restrict__ Wot,
    const float* __restrict__ bo,
    float* __restrict__ out)
{
    const int mt0 = blockIdx.x * 64;
    const int n0  = blockIdx.y * 64;
    const unsigned short* A = Z + (size_t)mt0 * DD;
    const unsigned short* Bw = Wot + (size_t)n0 * DD;

    // slot: [A0 2048][A1 2048][B0 2048][B1 2048] shorts = 16KB; ring of 3
    __shared__ unsigned short smem[3 * 8192];

    const int t = threadIdx.x;
    const int l = t & 63, w4 = t >> 6;
    const int l16 = l & 15, quad = l >> 4;
    const int swz = (l16 >> 1) & 3;

    f32x4 acc[4] = {};

    // prologue: slots 0 (k=0..63) and 1 (k=64..127) in flight: 8 DMA/wave
    #pragma unroll
    for (int s = 0; s < 2; s++) {
        unsigned short* sl = smem + s * 8192;
        stage64(sl,        A  + s * 64,      w4, l);
        stage64(sl + 2048, A  + s * 64 + 32, w4, l);
        stage64(sl + 4096, Bw + s * 64,      w4, l);
        stage64(sl + 6144, Bw + s * 64 + 32, w4, l);
    }

    for (int it = 0; it < 12; ++it) {
        unsigned short* Ac = smem + (it % 3) * 8192;
        unsigned short* Bc = Ac + 4096;
        if (it < 11) asm volatile("s_waitcnt vmcnt(4)" ::: "memory");
        else         asm volatile("s_waitcnt vmcnt(0)" ::: "memory");
        __builtin_amdgcn_s_barrier();
        if (it < 10) {
            unsigned short* An = smem + ((it + 2) % 3) * 8192;
            stage64(An,        A  + (it + 2) * 64,      w4, l);
            stage64(An + 2048, A  + (it + 2) * 64 + 32, w4, l);
            stage64(An + 4096, Bw + (it + 2) * 64,      w4, l);
            stage64(An + 6144, Bw + (it + 2) * 64 + 32, w4, l);
        }
        #pragma unroll
        for (int kk = 0; kk < 2; kk++) {
            bfrag af = *reinterpret_cast<const bfrag*>(
                &Ac[kk * 2048 + (w4 * 16 + l16) * 32 + ((quad ^ swz) * 8)]);
            #pragma unroll
            for (int ni = 0; ni < 4; ni++) {
                bfrag bg = *reinterpret_cast<const bfrag*>(
                    &Bc[kk * 2048 + (ni * 16 + l16) * 32 + ((quad ^ swz) * 8)]);
                acc[ni] = __builtin_amdgcn_mfma_f32_16x16x32_bf16(af, bg, acc[ni], 0, 0, 0);
            }
        }
    }

    #pragma unroll
    for (int ni = 0; ni < 4; ni++) {
        int n = n0 + ni * 16 + l16;
        float bv0 = bo[n];
        #pragma unroll
        for (int r = 0; r < 4; r++) {
            int m = mt0 + w4 * 16 + quad * 4 + r;
            out[(size_t)m * DD + n] = acc[ni][r] + bv0;
        }
    }
}

extern "C" void kernel_launch(void* const* d_in, const int* in_sizes, int n_in,
                              void* d_out, int out_size, void* d_ws, size_t ws_size,
                              hipStream_t stream) {
    const float* Xq = (const float*)d_in[0];
    const float* Xk = (const float*)d_in[1];
    const float* Xv = (const float*)d_in[2];
    const float* Wq = (const float*)d_in[3];
    const float* Wk = (const float*)d_in[4];
    const float* Wv = (const float*)d_in[5];
    const float* Wo = (const float*)d_in[6];
    const float* bq = (const float*)d_in[7];
    const float* bk = (const float*)d_in[8];
    const float* bv = (const float*)d_in[9];
    const float* bo = (const float*)d_in[10];
    float* out = (float*)d_out;

    const size_t seg = (size_t)BB * HH * SS * DHH;   // 3,145,728 bf16 elems
    unsigned short* q   = (unsigned short*)d_ws;
    unsigned short* k   = q + seg;
    unsigned short* v   = k + seg;
    unsigned short* z   = v + seg;
    unsigned short* Wt  = z + seg;                    // 3*768*768
    unsigned short* Wot = Wt + (size_t)3 * DD * DD;   // 768*768
    float2* rope = (float2*)(Wot + (size_t)DD * DD);  // 2048*32 float2
    unsigned short* Xbf = (unsigned short*)(rope + 2048 * 32); // 3*4096*768

    pack_kernel<<<dim3(3136), 256, 0, stream>>>(Xq, Xk, Xv, Wq, Wk, Wv, Wo, Wt, Wot, rope, Xbf);
    qkv_gemm_kernel<<<dim3(MM / 128, DD / 64, 3), 256, 0, stream>>>(
        Xbf, Wt, bq, bk, bv, rope, q, k, v);
    attn_kernel<<<dim3(SS / 64, HH, BB), 256, 0, stream>>>(q, k, v, z);
    out_gemm_kernel<<<dim3(MM / 64, DD / 64), 256, 0, stream>>>(z, Wot, bo, out);
}

// Round 14
// 160.222 us; speedup vs baseline: 1.0536x; 1.0021x over previous
//
#include <hip/hip_runtime.h>
#include <hip/hip_bf16.h>

#define BB 2
#define SS 2048
#define DD 768
#define HH 12
#define DHH 64
#define WIN 128
#define MM (BB*SS)

typedef __attribute__((ext_vector_type(8))) short bfrag;
typedef __attribute__((ext_vector_type(4))) float f32x4;
typedef __attribute__((ext_vector_type(4))) short s16x4;

#define AS3(p) ((__attribute__((address_space(3))) void*)(p))
#define AS1(p) ((const __attribute__((address_space(1))) void*)(p))

__device__ inline unsigned short f2bf(float f) {
    union { __hip_bfloat16 h; unsigned short u; } cv;
    cv.h = __float2bfloat16(f);
    return cv.u;
}

// Stage a R x 32 bf16 tile (row-major, global stride DD) into LDS via DMA,
// 16B chunks XOR-swizzled: chunk cs at row goes to slot cs ^ ((row>>1)&3).
__device__ inline void stage128(unsigned short* dst, const unsigned short* src,
                                int w4, int l) {
    #pragma unroll
    for (int j = 0; j < 2; j++) {
        int eoff = (w4 * 2 + j) * 512;
        int e = eoff + l * 8;
        int row = e >> 5;
        int k8 = ((e >> 3) & 3) ^ ((row >> 1) & 3);
        __builtin_amdgcn_global_load_lds(AS1(src + (size_t)row * DD + k8 * 8),
                                         AS3(dst + eoff), 16, 0, 0);
    }
}
__device__ inline void stage64(unsigned short* dst, const unsigned short* src,
                               int w4, int l) {
    int eoff = w4 * 512;
    int e = eoff + l * 8;
    int row = e >> 5;
    int k8 = ((e >> 3) & 3) ^ ((row >> 1) & 3);
    __builtin_amdgcn_global_load_lds(AS1(src + (size_t)row * DD + k8 * 8),
                                     AS3(dst + eoff), 16, 0, 0);
}

// ---------------- Kernel 0: pack (round-3 verified) ----------------
// [0,432): W_{Q,K,V} -> Wt ; [432,576): W_O -> Wot ; [576,832): rope ;
// [832,3136): X fp32 -> bf16
__global__ __launch_bounds__(256) void pack_kernel(
    const float* __restrict__ Xq, const float* __restrict__ Xk, const float* __restrict__ Xv,
    const float* __restrict__ Wq, const float* __restrict__ Wk, const float* __restrict__ Wv,
    const float* __restrict__ Wo,
    unsigned short* __restrict__ Wt, unsigned short* __restrict__ Wot,
    float2* __restrict__ rope, unsigned short* __restrict__ Xbf)
{
    __shared__ float T[64][65];
    const int bid = blockIdx.x, t = threadIdx.x;
    if (bid < 432) {
        int proj = bid / 144, rem = bid % 144;
        int h = rem / 12, d0 = (rem % 12) * 64;
        const float* src = (proj == 0 ? Wq : (proj == 1 ? Wk : Wv)) + (size_t)h * DD * DHH;
        int row = t >> 2, c0 = (t & 3) * 16;
        const float4* p4 = reinterpret_cast<const float4*>(src + (size_t)(d0 + row) * DHH + c0);
        float4 x0 = p4[0], x1 = p4[1], x2 = p4[2], x3 = p4[3];
        float* tr = &T[row][c0];
        tr[0]=x0.x; tr[1]=x0.y; tr[2]=x0.z; tr[3]=x0.w;
        tr[4]=x1.x; tr[5]=x1.y; tr[6]=x1.z; tr[7]=x1.w;
        tr[8]=x2.x; tr[9]=x2.y; tr[10]=x2.z; tr[11]=x2.w;
        tr[12]=x3.x; tr[13]=x3.y; tr[14]=x3.z; tr[15]=x3.w;
        __syncthreads();
        int dh = t >> 2;
        unsigned short tmp[16];
        #pragma unroll
        for (int j = 0; j < 16; j++) tmp[j] = f2bf(T[c0 + j][dh]);
        unsigned short* dst = Wt + (size_t)proj * DD * DD + (size_t)(h * 64 + dh) * DD + d0 + c0;
        *reinterpret_cast<bfrag*>(dst)     = *reinterpret_cast<bfrag*>(tmp);
        *reinterpret_cast<bfrag*>(dst + 8) = *reinterpret_cast<bfrag*>(tmp + 8);
    } else if (bid < 576) {
        int id2 = bid - 432;
        int k0 = (id2 / 12) * 64, n0 = (id2 % 12) * 64;
        int row = t >> 2, c0 = (t & 3) * 16;
        const float4* p4 = reinterpret_cast<const float4*>(Wo + (size_t)(k0 + row) * DD + n0 + c0);
        float4 x0 = p4[0], x1 = p4[1], x2 = p4[2], x3 = p4[3];
        float* tr = &T[row][c0];
        tr[0]=x0.x; tr[1]=x0.y; tr[2]=x0.z; tr[3]=x0.w;
        tr[4]=x1.x; tr[5]=x1.y; tr[6]=x1.z; tr[7]=x1.w;
        tr[8]=x2.x; tr[9]=x2.y; tr[10]=x2.z; tr[11]=x2.w;
        tr[12]=x3.x; tr[13]=x3.y; tr[14]=x3.z; tr[15]=x3.w;
        __syncthreads();
        int nr = t >> 2;
        unsigned short tmp[16];
        #pragma unroll
        for (int j = 0; j < 16; j++) tmp[j] = f2bf(T[c0 + j][nr]);
        unsigned short* dst = Wot + (size_t)(n0 + nr) * DD + k0 + c0;
        *reinterpret_cast<bfrag*>(dst)     = *reinterpret_cast<bfrag*>(tmp);
        *reinterpret_cast<bfrag*>(dst + 8) = *reinterpret_cast<bfrag*>(tmp + 8);
    } else if (bid < 832) {
        int idx = (bid - 576) * 256 + t;   // p in [0,2048), i2 in [0,32)
        int p = idx >> 5, i2 = idx & 31;
        float inv_freq = exp2f(-(float)i2 * (13.287712379549449f / 32.0f));
        float s, c;
        sincosf((float)p * inv_freq, &s, &c);
        rope[idx] = make_float2(s, c);
    } else {
        int i = bid - 832;                  // 2304 blocks x 4096 elems
        int proj = i / 768;
        size_t off = (size_t)(i % 768) * 4096 + t * 16;
        const float* src = (proj == 0 ? Xq : (proj == 1 ? Xk : Xv)) + off;
        const float4* p4 = reinterpret_cast<const float4*>(src);
        float4 a0 = p4[0], a1 = p4[1], a2 = p4[2], a3 = p4[3];
        unsigned short u[16];
        u[0]=f2bf(a0.x); u[1]=f2bf(a0.y); u[2]=f2bf(a0.z); u[3]=f2bf(a0.w);
        u[4]=f2bf(a1.x); u[5]=f2bf(a1.y); u[6]=f2bf(a1.z); u[7]=f2bf(a1.w);
        u[8]=f2bf(a2.x); u[9]=f2bf(a2.y); u[10]=f2bf(a2.z); u[11]=f2bf(a2.w);
        u[12]=f2bf(a3.x); u[13]=f2bf(a3.y); u[14]=f2bf(a3.z); u[15]=f2bf(a3.w);
        unsigned short* dst = Xbf + (size_t)proj * MM * DD + off;
        *reinterpret_cast<bfrag*>(dst)     = *reinterpret_cast<bfrag*>(u);
        *reinterpret_cast<bfrag*>(dst + 8) = *reinterpret_cast<bfrag*>(u + 8);
    }
}

// ---------------- Kernel 1: QKV GEMM, 128x64 tile, pure-DMA (round-7 verified) -
// 3D grid (32,12,3): natural order already gives W-panel sharing to consecutive
// blocks (x fastest). 1152 blocks, 36KB LDS -> 4 blocks/CU. Counted vmcnt(3).
__global__ __launch_bounds__(256) void qkv_gemm_kernel(
    const unsigned short* __restrict__ Xbf,
    const unsigned short* __restrict__ Wt,
    const float* __restrict__ bq, const float* __restrict__ bk, const float* __restrict__ bv,
    const float2* __restrict__ rope,
    unsigned short* __restrict__ qo, unsigned short* __restrict__ ko, unsigned short* __restrict__ vo)
{
    const int mt0  = blockIdx.x * 128;
    const int n0   = blockIdx.y * 64;
    const int proj = blockIdx.z;
    const unsigned short* X = Xbf + (size_t)proj * MM * DD + (size_t)mt0 * DD;
    const unsigned short* W = Wt + (size_t)proj * DD * DD + (size_t)n0 * DD;
    const float* bias = proj == 0 ? bq : (proj == 1 ? bk : bv);

    // slot: A[0,4096) B[4096,6144) shorts; ring of 3 = 36864B
    __shared__ unsigned short smem[3 * 6144];

    const int t = threadIdx.x;
    const int l = t & 63, w4 = t >> 6;
    const int l16 = l & 15, quad = l >> 4;
    const int swz = (l16 >> 1) & 3;

    f32x4 acc[8] = {};

    // prologue: tiles 0,1 in flight (6 DMA/wave)
    stage128(smem,               X,      w4, l);
    stage64 (smem + 4096,        W,      w4, l);
    stage128(smem + 6144,        X + 32, w4, l);
    stage64 (smem + 6144 + 4096, W + 32, w4, l);

    for (int it = 0; it < 24; ++it) {
        unsigned short* Ac = smem + (it % 3) * 6144;
        unsigned short* Bc = Ac + 4096;
        if (it < 23) asm volatile("s_waitcnt vmcnt(3)" ::: "memory");
        else         asm volatile("s_waitcnt vmcnt(0)" ::: "memory");
        __builtin_amdgcn_s_barrier();
        if (it < 22) {
            unsigned short* An = smem + ((it + 2) % 3) * 6144;
            stage128(An,        X + (it + 2) * 32, w4, l);
            stage64 (An + 4096, W + (it + 2) * 32, w4, l);
        }
        bfrag af[2], bg[4];
        #pragma unroll
        for (int mi = 0; mi < 2; mi++)
            af[mi] = *reinterpret_cast<const bfrag*>(&Ac[(w4 * 32 + mi * 16 + l16) * 32 + ((quad ^ swz) * 8)]);
        #pragma unroll
        for (int ni = 0; ni < 4; ni++)
            bg[ni] = *reinterpret_cast<const bfrag*>(&Bc[(ni * 16 + l16) * 32 + ((quad ^ swz) * 8)]);
        #pragma unroll
        for (int mi = 0; mi < 2; mi++)
            #pragma unroll
            for (int ni = 0; ni < 4; ni++)
                acc[mi * 4 + ni] = __builtin_amdgcn_mfma_f32_16x16x32_bf16(af[mi], bg[ni], acc[mi * 4 + ni], 0, 0, 0);
    }
    __syncthreads();

    unsigned short* Ct = smem;
    const int b = mt0 >> 11;
    if (proj < 2) {
        // Ct stride 72: [128 p][64 n]
        #pragma unroll
        for (int ni = 0; ni < 4; ni++) {
            int nloc = ni * 16 + l16;          // 0..63
            int n = n0 + nloc;
            int dh = n & 63;                   // == nloc
            float bv0 = bias[n];
            float bv1 = bias[n ^ 32];
            float sgn = (dh & 32) ? 1.0f : -1.0f;
            const float2* rp = rope + (dh & 31);
            #pragma unroll
            for (int mi = 0; mi < 2; mi++)
                #pragma unroll
                for (int r = 0; r < 4; r++) {
                    int ploc = w4 * 32 + mi * 16 + quad * 4 + r;
                    int p = (mt0 + ploc) & (SS - 1);
                    float2 sc = rp[p << 5];
                    float val = acc[mi * 4 + ni][r] + bv0;
                    float pr  = acc[mi * 4 + (ni ^ 2)][r] + bv1;
                    Ct[ploc * 72 + nloc] = f2bf(val * sc.y + sgn * pr * sc.x);
                }
        }
        __syncthreads();
        unsigned short* dst = (proj == 0) ? qo : ko;
        const int h = n0 >> 6;
        #pragma unroll
        for (int jj = 0; jj < 4; jj++) {
            int id = jj * 256 + t;             // 0..1023
            int row = id >> 3, c = (id & 7) * 8;
            int p = (mt0 + row) & (SS - 1);
            bfrag vv = *reinterpret_cast<const bfrag*>(&Ct[row * 72 + c]);
            *reinterpret_cast<bfrag*>(dst + (((size_t)(b * HH + h) * SS + p) << 6) + (n0 & 63) + c) = vv;
        }
    } else {
        // Ct stride 136: [64 n][128 p] (transposed for V layout)
        #pragma unroll
        for (int ni = 0; ni < 4; ni++) {
            int nloc = ni * 16 + l16;
            float bv0 = bias[n0 + nloc];
            #pragma unroll
            for (int mi = 0; mi < 2; mi++)
                #pragma unroll
                for (int r = 0; r < 4; r++) {
                    int ploc = w4 * 32 + mi * 16 + quad * 4 + r;
                    Ct[nloc * 136 + ploc] = f2bf(acc[mi * 4 + ni][r] + bv0);
                }
        }
        __syncthreads();
        int p0 = mt0 & (SS - 1);
        const int h = n0 >> 6;
        #pragma unroll
        for (int jj = 0; jj < 4; jj++) {
            int id = jj * 256 + t;             // 0..1023
            int row = id >> 4, c = (id & 15) * 8;
            int dh = (n0 & 63) + row;          // n0 64-aligned => dh = row
            bfrag vv = *reinterpret_cast<const bfrag*>(&Ct[row * 136 + c]);
            *reinterpret_cast<bfrag*>(vo + (((size_t)(b * HH + h) * DHH + dh) << 11) + p0 + c) = vv;
        }
    }
}

// ---------------- Kernel 2: sliding-window attention, band-skip (round-7) ------
// V staged in LDS (insulates the PV MFMA operand chain from global latency;
// V-direct variant measured slightly worse in round 8).
__global__ __launch_bounds__(256) void attn_kernel(
    const unsigned short* __restrict__ q,
    const unsigned short* __restrict__ k,
    const unsigned short* __restrict__ v,
    unsigned short* __restrict__ z)
{
    const int qb = blockIdx.x * 64;
    const int h  = blockIdx.y;
    const int b  = blockIdx.z;
    const int kb = qb - WIN;   // may be negative: reads land in prior ws slab (masked)

    // K panels [0,12288); P aliases [0,12800); Vt [12800,25088)
    __shared__ unsigned short sA[25088];

    const int t = threadIdx.x;
    const int w4 = t >> 6, l = t & 63;
    const int l16 = l & 15, quad = l >> 4;
    const int swz = (l16 >> 1) & 3;

    const size_t qkbase = (size_t)(b * HH + h) * SS * DHH;
    const unsigned short* kp = (k + qkbase) + (ptrdiff_t)kb * DHH;
    const unsigned short* vp = (v + (size_t)(b * HH + h) * DHH * SS) + (ptrdiff_t)kb;

    #pragma unroll
    for (int j = 0; j < 6; j++) {
        int g = w4 * 6 + j;
        int panel = g >> 2, sub = g & 3;
        int rg = panel >> 1, kpart = panel & 1;
        int e = sub * 512 + l * 8;
        int row = e >> 5;
        int k8 = ((e >> 3) & 3) ^ ((row >> 1) & 3);
        __builtin_amdgcn_global_load_lds(
            AS1(kp + (size_t)(rg * 64 + row) * DHH + kpart * 32 + k8 * 8),
            AS3(sA + panel * 2048 + sub * 512), 16, 0, 0);
    }
    #pragma unroll
    for (int j = 0; j < 6; j++) {
        int g = w4 * 6 + j;
        int F = g * 64 + l;               // flat 16B-chunk id, 0..1535
        int d = F / 24, s = F % 24;
        int cs = s ^ (d & 7);
        __builtin_amdgcn_global_load_lds(
            AS1(vp + (size_t)d * SS + cs * 8),
            AS3(sA + 12800 + g * 512), 16, 0, 0);
    }
    bfrag qf[2];
    #pragma unroll
    for (int kk = 0; kk < 2; kk++)
        qf[kk] = *reinterpret_cast<const bfrag*>(
            q + qkbase + (size_t)(qb + 16 * w4 + l16) * DHH + kk * 32 + quad * 8);

    __syncthreads();   // K + V resident

    f32x4 sacc[9] = {};
    __builtin_amdgcn_s_setprio(1);
    #pragma unroll
    for (int kk = 0; kk < 2; kk++)
        #pragma unroll
        for (int j = 0; j < 9; j++) {
            int kr = 16 * (w4 + j) + l16;
            bfrag bf = *reinterpret_cast<const bfrag*>(
                &sA[(((kr >> 6) * 2 + kk) * 2048) + (kr & 63) * 32 + ((quad ^ swz) * 8)]);
            sacc[j] = __builtin_amdgcn_mfma_f32_16x16x32_bf16(qf[kk], bf, sacc[j], 0, 0, 0);
        }
    __builtin_amdgcn_s_setprio(0);

    float mx[4] = {-3e38f, -3e38f, -3e38f, -3e38f};
    #pragma unroll
    for (int j = 0; j < 9; j++)
        #pragma unroll
        for (int r = 0; r < 4; r++) {
            int row = 16 * w4 + quad * 4 + r;
            int c = 16 * (w4 + j) + l16;
            bool valid = (c > row) && (c <= row + WIN) && (kb + c >= 0);
            float s = valid ? sacc[j][r] * 0.125f : -3e38f;
            sacc[j][r] = s;
            mx[r] = fmaxf(mx[r], s);
        }
    #pragma unroll
    for (int off = 1; off < 16; off <<= 1)
        #pragma unroll
        for (int r = 0; r < 4; r++) mx[r] = fmaxf(mx[r], __shfl_xor(mx[r], off, 64));
    float sum[4] = {0.f, 0.f, 0.f, 0.f};
    #pragma unroll
    for (int j = 0; j < 9; j++)
        #pragma unroll
        for (int r = 0; r < 4; r++) {
            float p = __expf(sacc[j][r] - mx[r]);
            sacc[j][r] = p;
            sum[r] += p;
        }
    #pragma unroll
    for (int off = 1; off < 16; off <<= 1)
        #pragma unroll
        for (int r = 0; r < 4; r++) sum[r] += __shfl_xor(sum[r], off, 64);
    float inv[4];
    #pragma unroll
    for (int r = 0; r < 4; r++) inv[r] = 1.0f / sum[r];

    __syncthreads();   // all K reads done before P overwrites that region

    unsigned short* Ps = sA;
    #pragma unroll
    for (int j = 0; j < 9; j++)
        #pragma unroll
        for (int r = 0; r < 4; r++)
            Ps[(16 * w4 + quad * 4 + r) * 200 + 16 * (w4 + j) + l16] = f2bf(sacc[j][r] * inv[r]);
    // zero the single tile inside the PV read-window that QK^T skipped
    {
        int mtz = (w4 & 1) ? (w4 - 1) : (w4 + 9);
        #pragma unroll
        for (int r = 0; r < 4; r++)
            Ps[(16 * w4 + quad * 4 + r) * 200 + 16 * mtz + l16] = 0;
    }

    unsigned short* Vt = sA + 12800;
    f32x4 zacc[4] = {};
    __builtin_amdgcn_s_setprio(1);
    #pragma unroll
    for (int ji = 0; ji < 5; ji++) {
        int ci = (w4 >> 1) + ji;
        bfrag pb = *reinterpret_cast<const bfrag*>(
            &Ps[(16 * w4 + l16) * 200 + ci * 32 + quad * 8]);
        #pragma unroll
        for (int mt = 0; mt < 4; mt++) {
            int d = 16 * mt + l16;
            bfrag va = *reinterpret_cast<const bfrag*>(
                &Vt[d * 192 + (((ci * 4 + quad) ^ (l16 & 7)) * 8)]);
            zacc[mt] = __builtin_amdgcn_mfma_f32_16x16x32_bf16(va, pb, zacc[mt], 0, 0, 0);
        }
    }
    __builtin_amdgcn_s_setprio(0);
    size_t zrow = ((size_t)(b * SS + qb + 16 * w4 + l16)) * (HH * DHH) + h * DHH;
    #pragma unroll
    for (int mt = 0; mt < 4; mt++) {
        s16x4 pk;
        pk[0] = (short)f2bf(zacc[mt][0]);
        pk[1] = (short)f2bf(zacc[mt][1]);
        pk[2] = (short)f2bf(zacc[mt][2]);
        pk[3] = (short)f2bf(zacc[mt][3]);
        *reinterpret_cast<s16x4*>(z + zrow + 16 * mt + quad * 4) = pk;
    }
}

// ---------------- Kernel 3: output projection, 64x64 tile, BK=64 (round-3) ----
__global__ __launch_bounds__(256) void out_gemm_kernel(
    const unsigned short* __restrict__ Z,
    const unsigned short* __restrict__ Wot,
    const float* __restrict__ bo,
    float* __restrict__ out)
{
    const int mt0 = blockIdx.x * 64;
    const int n0  = blockIdx.y * 64;
    const unsigned short* A = Z + (size_t)mt0 * DD;
    const unsigned short* Bw = Wot + (size_t)n0 * DD;

    // slot: [A0 2048][A1 2048][B0 2048][B1 2048] shorts = 16KB; ring of 3
    __shared__ unsigned short smem[3 * 8192];

    const int t = threadIdx.x;
    const int l = t & 63, w4 = t >> 6;
    const int l16 = l & 15, quad = l >> 4;
    const int swz = (l16 >> 1) & 3;

    f32x4 acc[4] = {};

    // prologue: slots 0 (k=0..63) and 1 (k=64..127) in flight: 8 DMA/wave
    #pragma unroll
    for (int s = 0; s < 2; s++) {
        unsigned short* sl = smem + s * 8192;
        stage64(sl,        A  + s * 64,      w4, l);
        stage64(sl + 2048, A  + s * 64 + 32, w4, l);
        stage64(sl + 4096, Bw + s * 64,      w4, l);
        stage64(sl + 6144, Bw + s * 64 + 32, w4, l);
    }

    for (int it = 0; it < 12; ++it) {
        unsigned short* Ac = smem + (it % 3) * 8192;
        unsigned short* Bc = Ac + 4096;
        if (it < 11) asm volatile("s_waitcnt vmcnt(4)" ::: "memory");
        else         asm volatile("s_waitcnt vmcnt(0)" ::: "memory");
        __builtin_amdgcn_s_barrier();
        if (it < 10) {
            unsigned short* An = smem + ((it + 2) % 3) * 8192;
            stage64(An,        A  + (it + 2) * 64,      w4, l);
            stage64(An + 2048, A  + (it + 2) * 64 + 32, w4, l);
            stage64(An + 4096, Bw + (it + 2) * 64,      w4, l);
            stage64(An + 6144, Bw + (it + 2) * 64 + 32, w4, l);
        }
        #pragma unroll
        for (int kk = 0; kk < 2; kk++) {
            bfrag af = *reinterpret_cast<const bfrag*>(
                &Ac[kk * 2048 + (w4 * 16 + l16) * 32 + ((quad ^ swz) * 8)]);
            #pragma unroll
            for (int ni = 0; ni < 4; ni++) {
                bfrag bg = *reinterpret_cast<const bfrag*>(
                    &Bc[kk * 2048 + (ni * 16 + l16) * 32 + ((quad ^ swz) * 8)]);
                acc[ni] = __builtin_amdgcn_mfma_f32_16x16x32_bf16(af, bg, acc[ni], 0, 0, 0);
            }
        }
    }

    #pragma unroll
    for (int ni = 0; ni < 4; ni++) {
        int n = n0 + ni * 16 + l16;
        float bv0 = bo[n];
        #pragma unroll
        for (int r = 0; r < 4; r++) {
            int m = mt0 + w4 * 16 + quad * 4 + r;
            out[(size_t)m * DD + n] = acc[ni][r] + bv0;
        }
    }
}

extern "C" void kernel_launch(void* const* d_in, const int* in_sizes, int n_in,
                              void* d_out, int out_size, void* d_ws, size_t ws_size,
                              hipStream_t stream) {
    const float* Xq = (const float*)d_in[0];
    const float* Xk = (const float*)d_in[1];
    const float* Xv = (const float*)d_in[2];
    const float* Wq = (const float*)d_in[3];
    const float* Wk = (const float*)d_in[4];
    const float* Wv = (const float*)d_in[5];
    const float* Wo = (const float*)d_in[6];
    const float* bq = (const float*)d_in[7];
    const float* bk = (const float*)d_in[8];
    const float* bv = (const float*)d_in[9];
    const float* bo = (const float*)d_in[10];
    float* out = (float*)d_out;

    const size_t seg = (size_t)BB * HH * SS * DHH;   // 3,145,728 bf16 elems
    unsigned short* q   = (unsigned short*)d_ws;
    unsigned short* k   = q + seg;
    unsigned short* v   = k + seg;
    unsigned short* z   = v + seg;
    unsigned short* Wt  = z + seg;                    // 3*768*768
    unsigned short* Wot = Wt + (size_t)3 * DD * DD;   // 768*768
    float2* rope = (float2*)(Wot + (size_t)DD * DD);  // 2048*32 float2
    unsigned short* Xbf = (unsigned short*)(rope + 2048 * 32); // 3*4096*768

    pack_kernel<<<dim3(3136), 256, 0, stream>>>(Xq, Xk, Xv, Wq, Wk, Wv, Wo, Wt, Wot, rope, Xbf);
    qkv_gemm_kernel<<<dim3(MM / 128, DD / 64, 3), 256, 0, stream>>>(
        Xbf, Wt, bq, bk, bv, rope, q, k, v);
    attn_kernel<<<dim3(SS / 64, HH, BB), 256, 0, stream>>>(q, k, v, z);
    out_gemm_kernel<<<dim3(MM / 64, DD / 64), 256, 0, stream>>>(z, Wot, bo, out);
}